// Round 10
// baseline (418.644 us; speedup 1.0000x reference)
//
#include <hip/hip_runtime.h>
#include <hip/hip_bf16.h>

// Problem constants (from reference)
#define NN 50000
#define EE 1600000
#define DIN 128

#define BKT_SHIFT 8                       // 256 nodes per bucket
#define NB ((NN + 255) >> 8)              // 196 buckets
#define BSLACK 9472                       // slack slots/bucket (mean 8418, +11 sigma)
#define CHUNK 4096                        // edges per binning workgroup (16/thread)

typedef _Float16 half_t;
typedef __attribute__((ext_vector_type(2))) _Float16 half2_t;
typedef __attribute__((ext_vector_type(4))) _Float16 half4_t;
typedef __attribute__((ext_vector_type(8))) _Float16 half8_t;
typedef __attribute__((ext_vector_type(4))) float float4_t;

// ---------------------------------------------------------------------------
// prep: build extended B^T hi/lo for each layer (W^T plus a 16-wide folded
// score tile: cols j<8 = ss head j, j>=8 = ds head j-8), and zero gcursor.
// ---------------------------------------------------------------------------
__device__ __forceinline__ void split_write(half_t* __restrict__ bh, half_t* __restrict__ bl,
                                            int idx, float v) {
    half_t h = (half_t)v;
    bh[idx] = h;
    bl[idx] = (half_t)(v - (float)h);
}

__device__ __forceinline__ void build_bt(const float* __restrict__ W,
                                         const float* __restrict__ as,
                                         const float* __restrict__ ad,
                                         half_t* __restrict__ Bh, half_t* __restrict__ Bl,
                                         int elem, int NCOL, int H) {
    int r = elem >> 7, k = elem & 127;  // Bt row r (out col / score), k in 0..127
    float v;
    if (r < NCOL) {
        v = W[k * NCOL + r];
    } else {
        int j = r - NCOL;
        v = 0.f;
        if (j < 8) {
            if (j < H) {
                float s = 0.f;
#pragma unroll
                for (int f = 0; f < 16; ++f) s += W[k * NCOL + j * 16 + f] * as[j * 16 + f];
                v = s;
            }
        } else {
            int hh = j - 8;
            if (hh < H) {
                float s = 0.f;
#pragma unroll
                for (int f = 0; f < 16; ++f) s += W[k * NCOL + hh * 16 + f] * ad[hh * 16 + f];
                v = s;
            }
        }
    }
    split_write(Bh, Bl, r * 128 + k, v);
}

#define T1 (144 * 128)
#define T3 (80 * 128)
__global__ __launch_bounds__(256) void prep_kernel(
    const float* __restrict__ W1, const float* __restrict__ W2, const float* __restrict__ W3,
    const float* __restrict__ as1, const float* __restrict__ ad1,
    const float* __restrict__ as2, const float* __restrict__ ad2,
    const float* __restrict__ as3, const float* __restrict__ ad3,
    half_t* __restrict__ B1h, half_t* __restrict__ B1l,
    half_t* __restrict__ B2h, half_t* __restrict__ B2l,
    half_t* __restrict__ B3h, half_t* __restrict__ B3l,
    int* __restrict__ gcursor) {
    int id = blockIdx.x * 256 + threadIdx.x;
    if (id < T1) {
        build_bt(W1, as1, ad1, B1h, B1l, id, 128, 8);
    } else if (id < 2 * T1) {
        build_bt(W2, as2, ad2, B2h, B2l, id - T1, 128, 8);
    } else if (id < 2 * T1 + T3) {
        build_bt(W3, as3, ad3, B3h, B3l, id - 2 * T1, 64, 4);
    } else {
        int i = id - (2 * T1 + T3);
        if (i < NB) gcursor[i] = 0;
    }
}

// ---------------------------------------------------------------------------
// CSR build: bucket binning (256 nodes/bucket -> ~84 B runs per (wg,bucket),
// low write amplification) -> per-bucket fine scatter into bucket-slack csr
// with per-node begin/end. Record packs (src<<8)|dloc (fits 24 bits).
// ---------------------------------------------------------------------------
__global__ __launch_bounds__(256) void bin_kernel(const int* __restrict__ A,
                                                  int* __restrict__ gcursor,
                                                  int* __restrict__ binned, int e, int n) {
    __shared__ int lcount[NB];
    __shared__ int lbase[NB];
    int chunk0 = blockIdx.x * CHUNK;
    int cend = chunk0 + CHUNK;
    if (cend > e + n) cend = e + n;
    for (int i = threadIdx.x; i < NB; i += 256) lcount[i] = 0;
    __syncthreads();
    int sreg[16], dreg[16];
#pragma unroll
    for (int l = 0; l < 16; ++l) {
        int i = chunk0 + l * 256 + threadIdx.x;
        if (i < cend) {
            if (i < e) { sreg[l] = A[i]; dreg[l] = A[e + i]; }
            else       { sreg[l] = dreg[l] = i - e; }
            atomicAdd(&lcount[dreg[l] >> BKT_SHIFT], 1);
        } else {
            dreg[l] = -1;
        }
    }
    __syncthreads();
    for (int b = threadIdx.x; b < NB; b += 256) {
        int c = lcount[b];
        lbase[b] = c ? atomicAdd(&gcursor[b], c) : 0;
        lcount[b] = 0;
    }
    __syncthreads();
#pragma unroll
    for (int l = 0; l < 16; ++l) {
        if (dreg[l] >= 0) {
            int bkt = dreg[l] >> BKT_SHIFT;
            int pos = lbase[bkt] + atomicAdd(&lcount[bkt], 1);
            if (pos < BSLACK)
                binned[(size_t)bkt * BSLACK + pos] = (sreg[l] << 8) | (dreg[l] & 255);
        }
    }
}

__global__ __launch_bounds__(256) void fine_scatter(const int* __restrict__ binned,
                                                    const int* __restrict__ gcursor,
                                                    int* __restrict__ begE,
                                                    int* __restrict__ endE,
                                                    int* __restrict__ csr) {
    __shared__ int lc[256];
    __shared__ int scur[256];
    __shared__ int sscan[256];
    int b = blockIdx.x;
    int node0 = b << BKT_SHIFT;
    int cnt = gcursor[b];
    if (cnt > BSLACK) cnt = BSLACK;
    const int* bp = binned + (size_t)b * BSLACK;
    lc[threadIdx.x] = 0;
    __syncthreads();
    for (int j = threadIdx.x; j < cnt; j += 256) atomicAdd(&lc[bp[j] & 255], 1);
    __syncthreads();
    // 256-entry inclusive scan (Hillis-Steele)
    int c = lc[threadIdx.x];
    sscan[threadIdx.x] = c;
    __syncthreads();
    for (int off = 1; off < 256; off <<= 1) {
        int u = (threadIdx.x >= (unsigned)off) ? sscan[threadIdx.x - off] : 0;
        __syncthreads();
        sscan[threadIdx.x] += u;
        __syncthreads();
    }
    {
        int begin = b * BSLACK + sscan[threadIdx.x] - c;  // exclusive, bucket-local
        scur[threadIdx.x] = begin;
        int node = node0 + threadIdx.x;
        if (node < NN) {
            begE[node] = begin;
            endE[node] = begin + c;
        }
    }
    __syncthreads();
    for (int j = threadIdx.x; j < cnt; j += 256) {
        int v = bp[j];
        int pos = atomicAdd(&scur[v & 255], 1);
        csr[pos] = v >> 8;
    }
}

// ---------------------------------------------------------------------------
// Split-fp16 MFMA GEMM with folded score columns (unchanged from r9).
// ---------------------------------------------------------------------------
template <int NTC, int H, bool A32>
__global__ __launch_bounds__(256) void gemm_mfma(
    const float* __restrict__ X32,
    const half_t* __restrict__ Ah, const half_t* __restrict__ Al,
    const half_t* __restrict__ Bth, const half_t* __restrict__ Btl,
    half_t* __restrict__ C16, float* __restrict__ ss, float* __restrict__ ds, int M) {
    constexpr int NCOL = NTC * 16;
    __shared__ __align__(16) half_t cs[4][16][NCOL + 8];
    int tid = threadIdx.x;
    int w = tid >> 6, lane = tid & 63;
    int m = lane & 15, q = lane >> 4;
    int row0 = blockIdx.x * 64 + w * 16;

    int ar = row0 + m;
    if (ar >= M) ar = M - 1;  // clamp (stores are guarded)
    half8_t ahf[4], alf[4];
    if constexpr (A32) {
        const float* px = X32 + (size_t)ar * 128 + q * 8;
#pragma unroll
        for (int k0 = 0; k0 < 4; ++k0) {
            float4 u0 = *(const float4*)(px + k0 * 32);
            float4 u1 = *(const float4*)(px + k0 * 32 + 4);
            float uv[8] = {u0.x, u0.y, u0.z, u0.w, u1.x, u1.y, u1.z, u1.w};
#pragma unroll
            for (int j = 0; j < 8; ++j) {
                half_t h = (half_t)uv[j];
                ahf[k0][j] = h;
                alf[k0][j] = (half_t)(uv[j] - (float)h);
            }
        }
    } else {
        const half_t* pa = Ah + (size_t)ar * 128 + q * 8;
        const half_t* pl = Al + (size_t)ar * 128 + q * 8;
#pragma unroll
        for (int k0 = 0; k0 < 4; ++k0) {
            ahf[k0] = *(const half8_t*)(pa + k0 * 32);
            alf[k0] = *(const half8_t*)(pl + k0 * 32);
        }
    }

    float4_t acc[NTC + 1];
#pragma unroll
    for (int nt = 0; nt <= NTC; ++nt) {
        acc[nt][0] = 0.f; acc[nt][1] = 0.f; acc[nt][2] = 0.f; acc[nt][3] = 0.f;
    }

#pragma unroll
    for (int nt = 0; nt <= NTC; ++nt) {
        const half_t* pbh = Bth + (size_t)(nt * 16 + m) * 128 + q * 8;
        const half_t* pbl = Btl + (size_t)(nt * 16 + m) * 128 + q * 8;
        half8_t bh[4], bl[4];
#pragma unroll
        for (int k0 = 0; k0 < 4; ++k0) {
            bh[k0] = *(const half8_t*)(pbh + k0 * 32);
            bl[k0] = *(const half8_t*)(pbl + k0 * 32);
        }
#pragma unroll
        for (int k0 = 0; k0 < 4; ++k0) {
            acc[nt] = __builtin_amdgcn_mfma_f32_16x16x32_f16(ahf[k0], bh[k0], acc[nt], 0, 0, 0);
            acc[nt] = __builtin_amdgcn_mfma_f32_16x16x32_f16(ahf[k0], bl[k0], acc[nt], 0, 0, 0);
            acc[nt] = __builtin_amdgcn_mfma_f32_16x16x32_f16(alf[k0], bh[k0], acc[nt], 0, 0, 0);
        }
    }

    // ss/ds straight from the score tile's D layout (col=m, row=q*4+r)
#pragma unroll
    for (int r = 0; r < 4; ++r) {
        int grow = row0 + q * 4 + r;
        if (grow < M) {
            float v = acc[NTC][r];
            if (m < H) ss[(size_t)grow * H + m] = v;
            else if (m >= 8 && m < 8 + H) ds[(size_t)grow * H + (m - 8)] = v;
        }
    }

    // C16 store via per-wave LDS bounce (own strip only; no block barrier)
#pragma unroll
    for (int nt = 0; nt < NTC; ++nt)
#pragma unroll
        for (int r = 0; r < 4; ++r)
            cs[w][q * 4 + r][nt * 16 + m] = (half_t)acc[nt][r];
    constexpr int LPR = NCOL / 8;   // lanes per row (16-B chunks)
    constexpr int RPP = 64 / LPR;   // rows per pass
    constexpr int NP = 16 / RPP;    // passes
    int rid = lane / LPR, cid = lane % LPR;
#pragma unroll
    for (int p = 0; p < NP; ++p) {
        int r = p * RPP + rid;
        int grow = row0 + r;
        half8_t v = *(const half8_t*)&cs[w][r][cid * 8];
        if (grow < M) *(half8_t*)(C16 + (size_t)grow * NCOL + cid * 8) = v;
    }
}

// ---------------------------------------------------------------------------
// Quarter-wave aggregation (r9 structure) over node range [n0, n1).
// Launched as two half-range dispatches per layer so rocprof top-5 exposes
// the mid-weight kernels (instrumentation; ~neutral perf).
// ---------------------------------------------------------------------------
template <int H, int F, bool MEAN, bool RELU>
__global__ __launch_bounds__(256) void aggregate_qw(
    const half_t* __restrict__ h, const float* __restrict__ ss, const float* __restrict__ dsc_arr,
    const int* __restrict__ csr, const int* __restrict__ begE, const int* __restrict__ endE,
    const float* __restrict__ bias, half_t* __restrict__ outh, half_t* __restrict__ outl,
    float* __restrict__ out, int n0, int n1) {
    constexpr int HF = H * F;
    constexpr int FPL = HF / 16;  // 8 (HF=128) or 4 (HF=64)
    int wave = n0 + blockIdx.x * (blockDim.x >> 6) + (threadIdx.x >> 6);
    int lane = threadIdx.x & 63;
    if (wave >= n1) return;
    int q = lane >> 4, ql = lane & 15;
    int hf = ql * FPL;
    int hh = hf / F;
    float dsc = dsc_arr[wave * H + hh];
    int begin = begE[wave], end = endE[wave];

    float ssum = 0.f;
    float acc[FPL];
#pragma unroll
    for (int k = 0; k < FPL; ++k) acc[k] = 0.f;

    int j = begin + q;  // this quarter's edge stream: j, j+4, j+8, ...
    for (; j + 12 < end; j += 16) {  // 4 edges per iteration
        int s0 = csr[j], s1 = csr[j + 4], s2 = csr[j + 8], s3 = csr[j + 12];
        float e0 = ss[s0 * H + hh], e1 = ss[s1 * H + hh];
        float e2 = ss[s2 * H + hh], e3 = ss[s3 * H + hh];
        const half_t* p0 = h + (size_t)s0 * HF + hf;
        const half_t* p1 = h + (size_t)s1 * HF + hf;
        const half_t* p2 = h + (size_t)s2 * HF + hf;
        const half_t* p3 = h + (size_t)s3 * HF + hf;
        e0 += dsc; e0 = (e0 > 0.f) ? e0 : 0.2f * e0;
        e1 += dsc; e1 = (e1 > 0.f) ? e1 : 0.2f * e1;
        e2 += dsc; e2 = (e2 > 0.f) ? e2 : 0.2f * e2;
        e3 += dsc; e3 = (e3 > 0.f) ? e3 : 0.2f * e3;
        float x0 = __expf(e0), x1 = __expf(e1), x2 = __expf(e2), x3 = __expf(e3);
        ssum += (x0 + x1) + (x2 + x3);
        if constexpr (FPL == 8) {
            half8_t t0 = *(const half8_t*)p0, t1 = *(const half8_t*)p1;
            half8_t t2 = *(const half8_t*)p2, t3 = *(const half8_t*)p3;
#pragma unroll
            for (int k = 0; k < 8; ++k) {
                acc[k] = fmaf(x0, (float)t0[k], acc[k]);
                acc[k] = fmaf(x1, (float)t1[k], acc[k]);
                acc[k] = fmaf(x2, (float)t2[k], acc[k]);
                acc[k] = fmaf(x3, (float)t3[k], acc[k]);
            }
        } else {
            half4_t t0 = *(const half4_t*)p0, t1 = *(const half4_t*)p1;
            half4_t t2 = *(const half4_t*)p2, t3 = *(const half4_t*)p3;
#pragma unroll
            for (int k = 0; k < 4; ++k) {
                acc[k] = fmaf(x0, (float)t0[k], acc[k]);
                acc[k] = fmaf(x1, (float)t1[k], acc[k]);
                acc[k] = fmaf(x2, (float)t2[k], acc[k]);
                acc[k] = fmaf(x3, (float)t3[k], acc[k]);
            }
        }
    }
    for (; j + 4 < end; j += 8) {  // 2 edges
        int s0 = csr[j], s1 = csr[j + 4];
        float e0 = ss[s0 * H + hh], e1 = ss[s1 * H + hh];
        const half_t* p0 = h + (size_t)s0 * HF + hf;
        const half_t* p1 = h + (size_t)s1 * HF + hf;
        e0 += dsc; e0 = (e0 > 0.f) ? e0 : 0.2f * e0;
        e1 += dsc; e1 = (e1 > 0.f) ? e1 : 0.2f * e1;
        float x0 = __expf(e0), x1 = __expf(e1);
        ssum += x0 + x1;
        if constexpr (FPL == 8) {
            half8_t t0 = *(const half8_t*)p0, t1 = *(const half8_t*)p1;
#pragma unroll
            for (int k = 0; k < 8; ++k) {
                acc[k] = fmaf(x0, (float)t0[k], acc[k]);
                acc[k] = fmaf(x1, (float)t1[k], acc[k]);
            }
        } else {
            half4_t t0 = *(const half4_t*)p0, t1 = *(const half4_t*)p1;
#pragma unroll
            for (int k = 0; k < 4; ++k) {
                acc[k] = fmaf(x0, (float)t0[k], acc[k]);
                acc[k] = fmaf(x1, (float)t1[k], acc[k]);
            }
        }
    }
    for (; j < end; j += 4) {  // tail: at most one edge per quarter
        int s = csr[j];
        float e = ss[s * H + hh] + dsc;
        e = (e > 0.f) ? e : 0.2f * e;
        float x = __expf(e);
        ssum += x;
        const half_t* hp = h + (size_t)s * HF + hf;
        if constexpr (FPL == 8) {
            half8_t t = *(const half8_t*)hp;
#pragma unroll
            for (int k = 0; k < 8; ++k) acc[k] = fmaf(x, (float)t[k], acc[k]);
        } else {
            half4_t t = *(const half4_t*)hp;
#pragma unroll
            for (int k = 0; k < 4; ++k) acc[k] = fmaf(x, (float)t[k], acc[k]);
        }
    }

    // merge the four quarters (lanes l, l^16, l^32, l^48 hold same features)
    ssum += __shfl_xor(ssum, 16, 64);
    ssum += __shfl_xor(ssum, 32, 64);
#pragma unroll
    for (int k = 0; k < FPL; ++k) {
        acc[k] += __shfl_xor(acc[k], 16, 64);
        acc[k] += __shfl_xor(acc[k], 32, 64);
    }

    float inv = 1.f / (ssum + 1e-16f);
    if constexpr (!MEAN) {
        // 128 outputs by 32 lanes; emit hi/lo fp16 split for the next MFMA GEMM
        if (lane < 32) {
            int k0 = (lane >> 4) * 4;  // 0 or 4
            int f = (lane & 15) * FPL + k0;
            float v[4];
#pragma unroll
            for (int i = 0; i < 4; ++i) {
                v[i] = acc[k0 + i] * inv + bias[f + i];
                if (RELU) v[i] = fmaxf(v[i], 0.f);
            }
            half4_t hh4, ll4;
#pragma unroll
            for (int i = 0; i < 4; ++i) {
                hh4[i] = (half_t)v[i];
                ll4[i] = (half_t)(v[i] - (float)hh4[i]);
            }
            *(half4_t*)(outh + (size_t)wave * HF + f) = hh4;
            *(half4_t*)(outl + (size_t)wave * HF + f) = ll4;
        }
    } else {
        // FPL == 4, H == 4: normalize per head, then mean over heads
        float val[FPL];
#pragma unroll
        for (int k = 0; k < FPL; ++k) {
            val[k] = acc[k] * inv;
            val[k] += __shfl_xor(val[k], 4, 64);
            val[k] += __shfl_xor(val[k], 8, 64);
        }
        if (lane < 4) {
            float v0 = val[0] * 0.25f + bias[lane * 4 + 0];
            float v1 = val[1] * 0.25f + bias[lane * 4 + 1];
            float v2 = val[2] * 0.25f + bias[lane * 4 + 2];
            float v3 = val[3] * 0.25f + bias[lane * 4 + 3];
            *(float4*)(out + (size_t)wave * F + lane * 4) = make_float4(v0, v1, v2, v3);
        }
    }
}

// ---------------------------------------------------------------------------
extern "C" void kernel_launch(void* const* d_in, const int* in_sizes, int n_in,
                              void* d_out, int out_size, void* d_ws, size_t ws_size,
                              hipStream_t stream) {
    const float* X  = (const float*)d_in[0];
    const int*   A  = (const int*)d_in[1];
    const float* W1 = (const float*)d_in[2];
    const float* as1 = (const float*)d_in[3];
    const float* ad1 = (const float*)d_in[4];
    const float* b1  = (const float*)d_in[5];
    const float* W2 = (const float*)d_in[6];
    const float* as2 = (const float*)d_in[7];
    const float* ad2 = (const float*)d_in[8];
    const float* b2  = (const float*)d_in[9];
    const float* W3 = (const float*)d_in[10];
    const float* as3 = (const float*)d_in[11];
    const float* ad3 = (const float*)d_in[12];
    const float* b3  = (const float*)d_in[13];

    const int N = NN, E = EE;
    const int Etot = E + N;

    char* p = (char*)d_ws;
    auto take = [&](size_t bytes) {
        char* r = p;
        p += (bytes + 255) & ~(size_t)255;
        return (void*)r;
    };
    half_t* C16   = (half_t*)take((size_t)N * 128 * 2);  // fp16 h rows (all layers)
    half_t* Ph    = (half_t*)take((size_t)N * 128 * 2);  // layer-1/2 activations hi
    half_t* Pl    = (half_t*)take((size_t)N * 128 * 2);  // layer-1/2 activations lo
    float* ssb    = (float*)take((size_t)N * 8 * 4);
    float* dsb    = (float*)take((size_t)N * 8 * 4);
    int* begE     = (int*)take((size_t)N * 4);
    int* endE     = (int*)take((size_t)N * 4);
    int* gcursor  = (int*)take((size_t)NB * 4);
    int* csr      = (int*)take((size_t)NB * BSLACK * 4);  // slack layout, 7.4 MB
    half_t* B1h   = (half_t*)take(144 * 128 * 2);
    half_t* B1l   = (half_t*)take(144 * 128 * 2);
    half_t* B2h   = (half_t*)take(144 * 128 * 2);
    half_t* B2l   = (half_t*)take(144 * 128 * 2);
    half_t* B3h   = (half_t*)take(80 * 128 * 2);
    half_t* B3l   = (half_t*)take(80 * 128 * 2);
    // binned slack regions alias Ph (7.4 MB < 12.8 MB); Ph is dead until the
    // layer-1 aggregate, which runs strictly after fine_scatter.
    int* binned   = (int*)Ph;

    // --- prep (W^T hi/lo + folded score cols, gcursor zero) + CSR build ---
    const int prepTotal = 2 * T1 + T3 + NB;
    prep_kernel<<<(prepTotal + 255) / 256, 256, 0, stream>>>(
        W1, W2, W3, as1, ad1, as2, ad2, as3, ad3,
        B1h, B1l, B2h, B2l, B3h, B3l, gcursor);
    bin_kernel<<<(Etot + CHUNK - 1) / CHUNK, 256, 0, stream>>>(A, gcursor, binned, E, N);
    fine_scatter<<<NB, 256, 0, stream>>>(binned, gcursor, begE, endE, csr);

    const int gemmRows = (N + 63) / 64;
    const int NH = 25000;                   // half-range split (instrumentation)
    const int halfBlocks = (NH + 3) / 4;

    // --- layer 1 (A = X fp32, split in-kernel) ---
    gemm_mfma<8, 8, true><<<gemmRows, 256, 0, stream>>>(X, nullptr, nullptr,
                                                        B1h, B1l, C16, ssb, dsb, N);
    aggregate_qw<8, 16, false, true><<<halfBlocks, 256, 0, stream>>>(
        C16, ssb, dsb, csr, begE, endE, b1, Ph, Pl, nullptr, 0, NH);
    aggregate_qw<8, 16, false, true><<<halfBlocks, 256, 0, stream>>>(
        C16, ssb, dsb, csr, begE, endE, b1, Ph, Pl, nullptr, NH, N);

    // --- layer 2 (agg writes back over Ph/Pl, dead after gemm2 reads them) ---
    gemm_mfma<8, 8, false><<<gemmRows, 256, 0, stream>>>(nullptr, Ph, Pl,
                                                         B2h, B2l, C16, ssb, dsb, N);
    aggregate_qw<8, 16, false, true><<<halfBlocks, 256, 0, stream>>>(
        C16, ssb, dsb, csr, begE, endE, b2, Ph, Pl, nullptr, 0, NH);
    aggregate_qw<8, 16, false, true><<<halfBlocks, 256, 0, stream>>>(
        C16, ssb, dsb, csr, begE, endE, b2, Ph, Pl, nullptr, NH, N);

    // --- layer 3 (H=4, mean over heads, no relu) ---
    gemm_mfma<4, 4, false><<<gemmRows, 256, 0, stream>>>(nullptr, Ph, Pl,
                                                         B3h, B3l, C16, ssb, dsb, N);
    aggregate_qw<4, 16, true, false><<<halfBlocks, 256, 0, stream>>>(
        C16, ssb, dsb, csr, begE, endE, b3, nullptr, nullptr, (float*)d_out, 0, NH);
    aggregate_qw<4, 16, true, false><<<halfBlocks, 256, 0, stream>>>(
        C16, ssb, dsb, csr, begE, endE, b3, nullptr, nullptr, (float*)d_out, NH, N);
}

// Round 11
// 345.257 us; speedup vs baseline: 1.2126x; 1.2126x over previous
//
#include <hip/hip_runtime.h>
#include <hip/hip_bf16.h>

// Problem constants (from reference)
#define NN 50000
#define EE 1600000
#define DIN 128

#define BKT_SHIFT 6                       // 64 nodes per bucket
#define NB ((NN + 63) >> 6)               // 782 buckets
#define BSLACK 2688                       // slack slots per bucket (mean 2110, +12.5 sigma)
#define CHUNK 4096                        // edges per binning workgroup (16/thread)

typedef _Float16 half_t;
typedef __attribute__((ext_vector_type(2))) _Float16 half2_t;
typedef __attribute__((ext_vector_type(4))) _Float16 half4_t;
typedef __attribute__((ext_vector_type(8))) _Float16 half8_t;
typedef __attribute__((ext_vector_type(4))) float float4_t;

// ---------------------------------------------------------------------------
// prep: build extended B^T hi/lo for each layer (W^T plus a 16-wide folded
// score tile: cols j<8 = ss head j, j>=8 = ds head j-8), and zero gcursor.
// ---------------------------------------------------------------------------
__device__ __forceinline__ void split_write(half_t* __restrict__ bh, half_t* __restrict__ bl,
                                            int idx, float v) {
    half_t h = (half_t)v;
    bh[idx] = h;
    bl[idx] = (half_t)(v - (float)h);
}

__device__ __forceinline__ void build_bt(const float* __restrict__ W,
                                         const float* __restrict__ as,
                                         const float* __restrict__ ad,
                                         half_t* __restrict__ Bh, half_t* __restrict__ Bl,
                                         int elem, int NCOL, int H) {
    int r = elem >> 7, k = elem & 127;  // Bt row r (out col / score), k in 0..127
    float v;
    if (r < NCOL) {
        v = W[k * NCOL + r];
    } else {
        int j = r - NCOL;
        v = 0.f;
        if (j < 8) {
            if (j < H) {
                float s = 0.f;
#pragma unroll
                for (int f = 0; f < 16; ++f) s += W[k * NCOL + j * 16 + f] * as[j * 16 + f];
                v = s;
            }
        } else {
            int hh = j - 8;
            if (hh < H) {
                float s = 0.f;
#pragma unroll
                for (int f = 0; f < 16; ++f) s += W[k * NCOL + hh * 16 + f] * ad[hh * 16 + f];
                v = s;
            }
        }
    }
    split_write(Bh, Bl, r * 128 + k, v);
}

#define T1 (144 * 128)
#define T3 (80 * 128)
__global__ __launch_bounds__(256) void prep_kernel(
    const float* __restrict__ W1, const float* __restrict__ W2, const float* __restrict__ W3,
    const float* __restrict__ as1, const float* __restrict__ ad1,
    const float* __restrict__ as2, const float* __restrict__ ad2,
    const float* __restrict__ as3, const float* __restrict__ ad3,
    half_t* __restrict__ B1h, half_t* __restrict__ B1l,
    half_t* __restrict__ B2h, half_t* __restrict__ B2l,
    half_t* __restrict__ B3h, half_t* __restrict__ B3l,
    int* __restrict__ gcursor) {
    int id = blockIdx.x * 256 + threadIdx.x;
    if (id < T1) {
        build_bt(W1, as1, ad1, B1h, B1l, id, 128, 8);
    } else if (id < 2 * T1) {
        build_bt(W2, as2, ad2, B2h, B2l, id - T1, 128, 8);
    } else if (id < 2 * T1 + T3) {
        build_bt(W3, as3, ad3, B3h, B3l, id - 2 * T1, 64, 4);
    } else {
        int i = id - (2 * T1 + T3);
        if (i < NB) gcursor[i] = 0;
    }
}

// ---------------------------------------------------------------------------
// CSR build (r9-proven): bucket binning -> per-bucket fine scatter into
// bucket-slack-layout csr with per-node begin/end. Packed src*64+dloc.
// ---------------------------------------------------------------------------
__global__ __launch_bounds__(256) void bin_kernel(const int* __restrict__ A,
                                                  int* __restrict__ gcursor,
                                                  int* __restrict__ binned, int e, int n) {
    __shared__ int lcount[NB];
    __shared__ int lbase[NB];
    int chunk0 = blockIdx.x * CHUNK;
    int cend = chunk0 + CHUNK;
    if (cend > e + n) cend = e + n;
    for (int i = threadIdx.x; i < NB; i += 256) lcount[i] = 0;
    __syncthreads();
    int sreg[16], dreg[16];
#pragma unroll
    for (int l = 0; l < 16; ++l) {
        int i = chunk0 + l * 256 + threadIdx.x;
        if (i < cend) {
            if (i < e) { sreg[l] = A[i]; dreg[l] = A[e + i]; }
            else       { sreg[l] = dreg[l] = i - e; }
            atomicAdd(&lcount[dreg[l] >> BKT_SHIFT], 1);
        } else {
            dreg[l] = -1;
        }
    }
    __syncthreads();
    for (int b = threadIdx.x; b < NB; b += 256) {
        int c = lcount[b];
        lbase[b] = c ? atomicAdd(&gcursor[b], c) : 0;
        lcount[b] = 0;
    }
    __syncthreads();
#pragma unroll
    for (int l = 0; l < 16; ++l) {
        if (dreg[l] >= 0) {
            int bkt = dreg[l] >> BKT_SHIFT;
            int pos = lbase[bkt] + atomicAdd(&lcount[bkt], 1);
            if (pos < BSLACK)
                binned[(size_t)bkt * BSLACK + pos] = (sreg[l] << 6) | (dreg[l] & 63);
        }
    }
}

__global__ __launch_bounds__(256) void fine_scatter(const int* __restrict__ binned,
                                                    const int* __restrict__ gcursor,
                                                    int* __restrict__ begE,
                                                    int* __restrict__ endE,
                                                    int* __restrict__ csr) {
    __shared__ int lc[64];
    __shared__ int scur[64];
    int b = blockIdx.x;
    int node0 = b << BKT_SHIFT;
    int cnt = gcursor[b];
    if (cnt > BSLACK) cnt = BSLACK;
    const int* bp = binned + (size_t)b * BSLACK;
    if (threadIdx.x < 64) lc[threadIdx.x] = 0;
    __syncthreads();
    for (int j = threadIdx.x; j < cnt; j += 256) atomicAdd(&lc[bp[j] & 63], 1);
    __syncthreads();
    if (threadIdx.x < 64) {  // wave-parallel exclusive scan over 64 counts
        int lane = threadIdx.x;
        int c = lc[lane];
        int v = c;
#pragma unroll
        for (int off = 1; off < 64; off <<= 1) {
            int u = __shfl_up(v, off, 64);
            if (lane >= off) v += u;
        }
        int begin = b * BSLACK + v - c;  // bucket-local slack layout
        scur[lane] = begin;
        int node = node0 + lane;
        if (node < NN) {
            begE[node] = begin;
            endE[node] = begin + c;
        }
    }
    __syncthreads();
    for (int j = threadIdx.x; j < cnt; j += 256) {
        int v = bp[j];
        int pos = atomicAdd(&scur[v & 63], 1);
        csr[pos] = v >> 6;
    }
}

// ---------------------------------------------------------------------------
// Split-fp16 MFMA GEMM, LDS-staged B in fragment order.
// C = Ah@Bh + Ah@Bl + Al@Bh (fp32 acc, near-fp32 accuracy). B^T extended with
// the folded score tile (r9). One cooperative load per block places both B
// arrays in LDS pre-swizzled to MFMA fragment order:
//   chunk P = (nt*4+k0)*64 + lane  holds  B^T[nt*16 + (lane&15)][(lane>>4)*8
//   + k0*32 .. +8)  -- so main-loop ds_read_b128 is lane-consecutive
//   (conflict-free), and all 4 waves share one B fetch instead of 4x VMEM.
// After a barrier the B region is reused as the C16 transpose bounce.
// ---------------------------------------------------------------------------
template <int NTC, int H, bool A32>
__global__ __launch_bounds__(256) void gemm_mfma(
    const float* __restrict__ X32,
    const half_t* __restrict__ Ah, const half_t* __restrict__ Al,
    const half_t* __restrict__ Bth, const half_t* __restrict__ Btl,
    half_t* __restrict__ C16, float* __restrict__ ss, float* __restrict__ ds, int M) {
    constexpr int NCOL = NTC * 16;
    constexpr int NR = NTC + 1;               // tiles incl. score tile
    constexpr int NCHUNK = NR * 256;          // 16B chunks per B array
    __shared__ __align__(16) half_t Bs[2][NR * 2048];  // 73.7 KB (NTC=8)
    int tid = threadIdx.x;
    int w = tid >> 6, lane = tid & 63;
    int m = lane & 15, q = lane >> 4;
    int row0 = blockIdx.x * 64 + w * 16;

    // cooperative fragment-ordered B load (each thread NR chunks per array)
    for (int P = tid; P < NCHUNK; P += 256) {
        int nt = P >> 8, k0 = (P >> 6) & 3, qq = (P >> 4) & 3, mm = P & 15;
        int src = (nt * 16 + mm) * 128 + qq * 8 + k0 * 32;  // half index
        *(half8_t*)&Bs[0][(size_t)P * 8] = *(const half8_t*)&Bth[src];
        *(half8_t*)&Bs[1][(size_t)P * 8] = *(const half8_t*)&Btl[src];
    }

    // A fragment (VMEM, per-wave) — overlaps the barrier
    int ar = row0 + m;
    if (ar >= M) ar = M - 1;  // clamp (stores are guarded)
    half8_t ahf[4], alf[4];
    if constexpr (A32) {
        const float* px = X32 + (size_t)ar * 128 + q * 8;
#pragma unroll
        for (int k0 = 0; k0 < 4; ++k0) {
            float4 u0 = *(const float4*)(px + k0 * 32);
            float4 u1 = *(const float4*)(px + k0 * 32 + 4);
            float uv[8] = {u0.x, u0.y, u0.z, u0.w, u1.x, u1.y, u1.z, u1.w};
#pragma unroll
            for (int j = 0; j < 8; ++j) {
                half_t h = (half_t)uv[j];
                ahf[k0][j] = h;
                alf[k0][j] = (half_t)(uv[j] - (float)h);
            }
        }
    } else {
        const half_t* pa = Ah + (size_t)ar * 128 + q * 8;
        const half_t* pl = Al + (size_t)ar * 128 + q * 8;
#pragma unroll
        for (int k0 = 0; k0 < 4; ++k0) {
            ahf[k0] = *(const half8_t*)(pa + k0 * 32);
            alf[k0] = *(const half8_t*)(pl + k0 * 32);
        }
    }

    __syncthreads();

    float4_t acc[NR];
#pragma unroll
    for (int nt = 0; nt < NR; ++nt) {
        acc[nt][0] = 0.f; acc[nt][1] = 0.f; acc[nt][2] = 0.f; acc[nt][3] = 0.f;
    }

#pragma unroll
    for (int nt = 0; nt < NR; ++nt) {
#pragma unroll
        for (int k0 = 0; k0 < 4; ++k0) {
            half8_t bh = *(const half8_t*)&Bs[0][(size_t)((nt * 4 + k0) * 64 + lane) * 8];
            half8_t bl = *(const half8_t*)&Bs[1][(size_t)((nt * 4 + k0) * 64 + lane) * 8];
            acc[nt] = __builtin_amdgcn_mfma_f32_16x16x32_f16(ahf[k0], bh, acc[nt], 0, 0, 0);
            acc[nt] = __builtin_amdgcn_mfma_f32_16x16x32_f16(ahf[k0], bl, acc[nt], 0, 0, 0);
            acc[nt] = __builtin_amdgcn_mfma_f32_16x16x32_f16(alf[k0], bh, acc[nt], 0, 0, 0);
        }
    }

    // ss/ds straight from the score tile's D layout (col=m, row=q*4+r)
#pragma unroll
    for (int r = 0; r < 4; ++r) {
        int grow = row0 + q * 4 + r;
        if (grow < M) {
            float v = acc[NTC][r];
            if (m < H) ss[(size_t)grow * H + m] = v;
            else if (m >= 8 && m < 8 + H) ds[(size_t)grow * H + (m - 8)] = v;
        }
    }

    // C16 store: reuse the B LDS region as transpose bounce (barrier first)
    __syncthreads();
    half_t* cs = (half_t*)Bs;  // [4][16][NCOL] strips, per-wave disjoint
#pragma unroll
    for (int nt = 0; nt < NTC; ++nt)
#pragma unroll
        for (int r = 0; r < 4; ++r)
            cs[(size_t)(w * 16 + q * 4 + r) * NCOL + nt * 16 + m] = (half_t)acc[nt][r];
    constexpr int LPR = NCOL / 8;   // lanes per row (16-B chunks)
    constexpr int RPP = 64 / LPR;   // rows per pass
    constexpr int NP = 16 / RPP;    // passes
    int rid = lane / LPR, cid = lane % LPR;
#pragma unroll
    for (int p = 0; p < NP; ++p) {
        int r = p * RPP + rid;
        int grow = row0 + r;
        half8_t v = *(const half8_t*)&cs[(size_t)(w * 16 + r) * NCOL + cid * 8];
        if (grow < M) *(half8_t*)(C16 + (size_t)grow * NCOL + cid * 8) = v;
    }
}

// ---------------------------------------------------------------------------
// Quarter-wave aggregation (r9 structure, full-range): 4 independent 16-lane
// edge streams per wave, no max-tracking, 4-edge unroll. Output: hi/lo fp16
// pair for layers 1-2, fp32 head-mean for layer 3.
// ---------------------------------------------------------------------------
template <int H, int F, bool MEAN, bool RELU>
__global__ __launch_bounds__(256) void aggregate_qw(
    const half_t* __restrict__ h, const float* __restrict__ ss, const float* __restrict__ dsc_arr,
    const int* __restrict__ csr, const int* __restrict__ begE, const int* __restrict__ endE,
    const float* __restrict__ bias, half_t* __restrict__ outh, half_t* __restrict__ outl,
    float* __restrict__ out, int n) {
    constexpr int HF = H * F;
    constexpr int FPL = HF / 16;  // 8 (HF=128) or 4 (HF=64)
    int wave = blockIdx.x * (blockDim.x >> 6) + (threadIdx.x >> 6);
    int lane = threadIdx.x & 63;
    if (wave >= n) return;
    int q = lane >> 4, ql = lane & 15;
    int hf = ql * FPL;
    int hh = hf / F;
    float dsc = dsc_arr[wave * H + hh];
    int begin = begE[wave], end = endE[wave];

    float ssum = 0.f;
    float acc[FPL];
#pragma unroll
    for (int k = 0; k < FPL; ++k) acc[k] = 0.f;

    int j = begin + q;  // this quarter's edge stream: j, j+4, j+8, ...
    for (; j + 12 < end; j += 16) {  // 4 edges per iteration
        int s0 = csr[j], s1 = csr[j + 4], s2 = csr[j + 8], s3 = csr[j + 12];
        float e0 = ss[s0 * H + hh], e1 = ss[s1 * H + hh];
        float e2 = ss[s2 * H + hh], e3 = ss[s3 * H + hh];
        const half_t* p0 = h + (size_t)s0 * HF + hf;
        const half_t* p1 = h + (size_t)s1 * HF + hf;
        const half_t* p2 = h + (size_t)s2 * HF + hf;
        const half_t* p3 = h + (size_t)s3 * HF + hf;
        e0 += dsc; e0 = (e0 > 0.f) ? e0 : 0.2f * e0;
        e1 += dsc; e1 = (e1 > 0.f) ? e1 : 0.2f * e1;
        e2 += dsc; e2 = (e2 > 0.f) ? e2 : 0.2f * e2;
        e3 += dsc; e3 = (e3 > 0.f) ? e3 : 0.2f * e3;
        float x0 = __expf(e0), x1 = __expf(e1), x2 = __expf(e2), x3 = __expf(e3);
        ssum += (x0 + x1) + (x2 + x3);
        if constexpr (FPL == 8) {
            half8_t t0 = *(const half8_t*)p0, t1 = *(const half8_t*)p1;
            half8_t t2 = *(const half8_t*)p2, t3 = *(const half8_t*)p3;
#pragma unroll
            for (int k = 0; k < 8; ++k) {
                acc[k] = fmaf(x0, (float)t0[k], acc[k]);
                acc[k] = fmaf(x1, (float)t1[k], acc[k]);
                acc[k] = fmaf(x2, (float)t2[k], acc[k]);
                acc[k] = fmaf(x3, (float)t3[k], acc[k]);
            }
        } else {
            half4_t t0 = *(const half4_t*)p0, t1 = *(const half4_t*)p1;
            half4_t t2 = *(const half4_t*)p2, t3 = *(const half4_t*)p3;
#pragma unroll
            for (int k = 0; k < 4; ++k) {
                acc[k] = fmaf(x0, (float)t0[k], acc[k]);
                acc[k] = fmaf(x1, (float)t1[k], acc[k]);
                acc[k] = fmaf(x2, (float)t2[k], acc[k]);
                acc[k] = fmaf(x3, (float)t3[k], acc[k]);
            }
        }
    }
    for (; j + 4 < end; j += 8) {  // 2 edges
        int s0 = csr[j], s1 = csr[j + 4];
        float e0 = ss[s0 * H + hh], e1 = ss[s1 * H + hh];
        const half_t* p0 = h + (size_t)s0 * HF + hf;
        const half_t* p1 = h + (size_t)s1 * HF + hf;
        e0 += dsc; e0 = (e0 > 0.f) ? e0 : 0.2f * e0;
        e1 += dsc; e1 = (e1 > 0.f) ? e1 : 0.2f * e1;
        float x0 = __expf(e0), x1 = __expf(e1);
        ssum += x0 + x1;
        if constexpr (FPL == 8) {
            half8_t t0 = *(const half8_t*)p0, t1 = *(const half8_t*)p1;
#pragma unroll
            for (int k = 0; k < 8; ++k) {
                acc[k] = fmaf(x0, (float)t0[k], acc[k]);
                acc[k] = fmaf(x1, (float)t1[k], acc[k]);
            }
        } else {
            half4_t t0 = *(const half4_t*)p0, t1 = *(const half4_t*)p1;
#pragma unroll
            for (int k = 0; k < 4; ++k) {
                acc[k] = fmaf(x0, (float)t0[k], acc[k]);
                acc[k] = fmaf(x1, (float)t1[k], acc[k]);
            }
        }
    }
    for (; j < end; j += 4) {  // tail: at most one edge per quarter
        int s = csr[j];
        float e = ss[s * H + hh] + dsc;
        e = (e > 0.f) ? e : 0.2f * e;
        float x = __expf(e);
        ssum += x;
        const half_t* hp = h + (size_t)s * HF + hf;
        if constexpr (FPL == 8) {
            half8_t t = *(const half8_t*)hp;
#pragma unroll
            for (int k = 0; k < 8; ++k) acc[k] = fmaf(x, (float)t[k], acc[k]);
        } else {
            half4_t t = *(const half4_t*)hp;
#pragma unroll
            for (int k = 0; k < 4; ++k) acc[k] = fmaf(x, (float)t[k], acc[k]);
        }
    }

    // merge the four quarters (lanes l, l^16, l^32, l^48 hold same features)
    ssum += __shfl_xor(ssum, 16, 64);
    ssum += __shfl_xor(ssum, 32, 64);
#pragma unroll
    for (int k = 0; k < FPL; ++k) {
        acc[k] += __shfl_xor(acc[k], 16, 64);
        acc[k] += __shfl_xor(acc[k], 32, 64);
    }

    float inv = 1.f / (ssum + 1e-16f);
    if constexpr (!MEAN) {
        // 128 outputs by 32 lanes; emit hi/lo fp16 split for the next MFMA GEMM
        if (lane < 32) {
            int k0 = (lane >> 4) * 4;  // 0 or 4
            int f = (lane & 15) * FPL + k0;
            float v[4];
#pragma unroll
            for (int i = 0; i < 4; ++i) {
                v[i] = acc[k0 + i] * inv + bias[f + i];
                if (RELU) v[i] = fmaxf(v[i], 0.f);
            }
            half4_t hh4, ll4;
#pragma unroll
            for (int i = 0; i < 4; ++i) {
                hh4[i] = (half_t)v[i];
                ll4[i] = (half_t)(v[i] - (float)hh4[i]);
            }
            *(half4_t*)(outh + (size_t)wave * HF + f) = hh4;
            *(half4_t*)(outl + (size_t)wave * HF + f) = ll4;
        }
    } else {
        // FPL == 4, H == 4: normalize per head, then mean over heads
        float val[FPL];
#pragma unroll
        for (int k = 0; k < FPL; ++k) {
            val[k] = acc[k] * inv;
            val[k] += __shfl_xor(val[k], 4, 64);
            val[k] += __shfl_xor(val[k], 8, 64);
        }
        if (lane < 4) {
            float v0 = val[0] * 0.25f + bias[lane * 4 + 0];
            float v1 = val[1] * 0.25f + bias[lane * 4 + 1];
            float v2 = val[2] * 0.25f + bias[lane * 4 + 2];
            float v3 = val[3] * 0.25f + bias[lane * 4 + 3];
            *(float4*)(out + (size_t)wave * F + lane * 4) = make_float4(v0, v1, v2, v3);
        }
    }
}

// ---------------------------------------------------------------------------
extern "C" void kernel_launch(void* const* d_in, const int* in_sizes, int n_in,
                              void* d_out, int out_size, void* d_ws, size_t ws_size,
                              hipStream_t stream) {
    const float* X  = (const float*)d_in[0];
    const int*   A  = (const int*)d_in[1];
    const float* W1 = (const float*)d_in[2];
    const float* as1 = (const float*)d_in[3];
    const float* ad1 = (const float*)d_in[4];
    const float* b1  = (const float*)d_in[5];
    const float* W2 = (const float*)d_in[6];
    const float* as2 = (const float*)d_in[7];
    const float* ad2 = (const float*)d_in[8];
    const float* b2  = (const float*)d_in[9];
    const float* W3 = (const float*)d_in[10];
    const float* as3 = (const float*)d_in[11];
    const float* ad3 = (const float*)d_in[12];
    const float* b3  = (const float*)d_in[13];

    const int N = NN, E = EE;
    const int Etot = E + N;

    char* p = (char*)d_ws;
    auto take = [&](size_t bytes) {
        char* r = p;
        p += (bytes + 255) & ~(size_t)255;
        return (void*)r;
    };
    half_t* C16   = (half_t*)take((size_t)N * 128 * 2);  // fp16 h rows (all layers)
    half_t* Ph    = (half_t*)take((size_t)N * 128 * 2);  // layer-1/2 activations hi
    half_t* Pl    = (half_t*)take((size_t)N * 128 * 2);  // layer-1/2 activations lo
    float* ssb    = (float*)take((size_t)N * 8 * 4);
    float* dsb    = (float*)take((size_t)N * 8 * 4);
    int* begE     = (int*)take((size_t)N * 4);
    int* endE     = (int*)take((size_t)N * 4);
    int* gcursor  = (int*)take((size_t)NB * 4);
    int* csr      = (int*)take((size_t)NB * BSLACK * 4);  // slack layout, 8.4 MB
    half_t* B1h   = (half_t*)take(144 * 128 * 2);
    half_t* B1l   = (half_t*)take(144 * 128 * 2);
    half_t* B2h   = (half_t*)take(144 * 128 * 2);
    half_t* B2l   = (half_t*)take(144 * 128 * 2);
    half_t* B3h   = (half_t*)take(80 * 128 * 2);
    half_t* B3l   = (half_t*)take(80 * 128 * 2);
    // binned slack regions alias Ph (8.4 MB < 12.8 MB); Ph is dead until the
    // layer-1 aggregate, which runs strictly after fine_scatter.
    int* binned   = (int*)Ph;

    // --- prep (W^T hi/lo + folded score cols, gcursor zero) + CSR build ---
    const int prepTotal = 2 * T1 + T3 + NB;
    prep_kernel<<<(prepTotal + 255) / 256, 256, 0, stream>>>(
        W1, W2, W3, as1, ad1, as2, ad2, as3, ad3,
        B1h, B1l, B2h, B2l, B3h, B3l, gcursor);
    bin_kernel<<<(Etot + CHUNK - 1) / CHUNK, 256, 0, stream>>>(A, gcursor, binned, E, N);
    fine_scatter<<<NB, 256, 0, stream>>>(binned, gcursor, begE, endE, csr);

    const int gemmRows = (N + 63) / 64;
    const int aggBlocks = (N + 3) / 4;

    // --- layer 1 (A = X fp32, split in-kernel) ---
    gemm_mfma<8, 8, true><<<gemmRows, 256, 0, stream>>>(X, nullptr, nullptr,
                                                        B1h, B1l, C16, ssb, dsb, N);
    aggregate_qw<8, 16, false, true>
        <<<aggBlocks, 256, 0, stream>>>(C16, ssb, dsb, csr, begE, endE, b1, Ph, Pl, nullptr, N);

    // --- layer 2 (agg writes back over Ph/Pl, dead after gemm2 reads them) ---
    gemm_mfma<8, 8, false><<<gemmRows, 256, 0, stream>>>(nullptr, Ph, Pl,
                                                         B2h, B2l, C16, ssb, dsb, N);
    aggregate_qw<8, 16, false, true>
        <<<aggBlocks, 256, 0, stream>>>(C16, ssb, dsb, csr, begE, endE, b2, Ph, Pl, nullptr, N);

    // --- layer 3 (H=4, mean over heads, no relu) ---
    gemm_mfma<4, 4, false><<<gemmRows, 256, 0, stream>>>(nullptr, Ph, Pl,
                                                         B3h, B3l, C16, ssb, dsb, N);
    aggregate_qw<4, 16, true, false>
        <<<aggBlocks, 256, 0, stream>>>(C16, ssb, dsb, csr, begE, endE, b3, nullptr, nullptr,
                                        (float*)d_out, N);
}